// Round 14
// baseline (591.485 us; speedup 1.0000x reference)
//
#include <hip/hip_runtime.h>

#define D_IN   768
#define NLAT   24576
#define BATCH  4096
#define K_TOP  64
#define MAXA   1024
#define DELTA  0.05f
#define THRESH 1.30f
#define CAND_MAX 512
#define MAXAMB 128
#define SLOTS  12

typedef float f32x4  __attribute__((ext_vector_type(4)));
typedef float f32x16 __attribute__((ext_vector_type(16)));
typedef short short8 __attribute__((ext_vector_type(8)));

// ---------------------------------------------------------------------------
__device__ __forceinline__ unsigned f2key(float f) {
    unsigned u = __float_as_uint(f);
    return (u & 0x80000000u) ? ~u : (u | 0x80000000u);
}
__device__ __forceinline__ float key2f(unsigned k) {
    unsigned u = (k & 0x80000000u) ? (k & 0x7fffffffu) : ~k;
    return __uint_as_float(u);
}
__device__ __forceinline__ unsigned short bf16hi(float f) {   // RNE f32->bf16
    unsigned u = __float_as_uint(f);
    unsigned r = u + 0x7fffu + ((u >> 16) & 1u);
    return (unsigned short)(r >> 16);
}
__device__ __forceinline__ float bf2f(unsigned short h) {
    return __uint_as_float(((unsigned)h) << 16);
}
__device__ __forceinline__ float binedge(int b) {
    return __uint_as_float((unsigned)(16288 + b) << 16);   // bin 0 edge = 1.25f
}

// ---------------------------------------------------------------------------
// One merged bf16 convert pass: x (with b_pre), W_enc, W_dec.
// ---------------------------------------------------------------------------
#define XCHUNKS (BATCH * D_IN / 4 / 256)   // 3072
#define WCHUNKS (NLAT * D_IN / 4 / 256)    // 18432

__global__ __launch_bounds__(256) void conv_all(const float4* __restrict__ x,
                                                const float* __restrict__ bpre,
                                                const float4* __restrict__ We,
                                                const float4* __restrict__ Wd,
                                                ushort4* __restrict__ xh,
                                                ushort4* __restrict__ wh,
                                                ushort4* __restrict__ wdh)
{
    const int b = blockIdx.x;
    if (b < XCHUNKS) {
        const int f = b * 256 + threadIdx.x;
        float4 v = x[f];
        const float4 bp = ((const float4*)bpre)[f % (D_IN / 4)];
        ushort4 h;
        h.x = bf16hi(v.x - bp.x);
        h.y = bf16hi(v.y - bp.y);
        h.z = bf16hi(v.z - bp.z);
        h.w = bf16hi(v.w - bp.w);
        xh[f] = h;
    } else if (b < XCHUNKS + WCHUNKS) {
        const int f = (b - XCHUNKS) * 256 + threadIdx.x;
        const float4 v = We[f];
        ushort4 h;
        h.x = bf16hi(v.x); h.y = bf16hi(v.y); h.z = bf16hi(v.z); h.w = bf16hi(v.w);
        wh[f] = h;
    } else {
        const int f = (b - XCHUNKS - WCHUNKS) * 256 + threadIdx.x;
        const float4 v = Wd[f];
        ushort4 h;
        h.x = bf16hi(v.x); h.y = bf16hi(v.y); h.z = bf16hi(v.z); h.w = bf16hi(v.w);
        wdh[f] = h;
    }
}

// ---------------------------------------------------------------------------
// bf16 encoder GEMM, 32x32x16 MFMA, fused z-zeroing + slot extraction,
// nontemporal output stores (r13-verified).
// ---------------------------------------------------------------------------
#define GBM 128
#define GBN 128
#define GBK 64
#define LROW (GBK + 8)
#define NWG  ((NLAT / GBN) * (BATCH / GBM))   // 6144
#define NBLKN (NLAT / GBN)                    // 192

__global__ __launch_bounds__(256) void enc_gemm_fused(const unsigned short* __restrict__ xh,
                                                      const unsigned short* __restrict__ wh,
                                                      float* __restrict__ z_pre,
                                                      float* __restrict__ z,
                                                      int* __restrict__ cnt_blk,   // [NBLKN][BATCH]
                                                      int2* __restrict__ slot_iv)  // [BATCH][NBLKN][SLOTS]
{
    __shared__ unsigned short Ah[GBM][LROW];
    __shared__ unsigned short Bh[GBN][LROW];
    __shared__ int rowcnt[GBM];

    const int tid = threadIdx.x;
    const int bid = blockIdx.x;
    const int swz = (bid & 7) * (NWG / 8) + (bid >> 3);
    const int bn = (swz % NBLKN) * GBN;
    const int bm = (swz / NBLKN) * GBM;
    const int blkn = bn / GBN;

    const int lane = tid & 63;
    const int wv = tid >> 6;
    const int wr = (wv >> 1) * 64;
    const int wc = (wv & 1) * 64;
    const int l31 = lane & 31;
    const int lh  = lane >> 5;

    int srow[4], sko[4];
    const unsigned short* pxa[4];
    const unsigned short* pwb[4];
    #pragma unroll
    for (int q = 0; q < 4; ++q) {
        const int c = q * 256 + tid;
        srow[q] = c >> 3;
        sko[q]  = (c & 7) * 8;
        pxa[q] = xh + (size_t)(bm + srow[q]) * D_IN + sko[q];
        pwb[q] = wh + (size_t)(bn + srow[q]) * D_IN + sko[q];
    }

    f32x16 acc[2][2];
    #pragma unroll
    for (int i = 0; i < 2; ++i)
        #pragma unroll
        for (int j = 0; j < 2; ++j)
            #pragma unroll
            for (int e = 0; e < 16; ++e) acc[i][j][e] = 0.0f;

    for (int k0 = 0; k0 < D_IN; k0 += GBK) {
        short8 va[4], vb[4];
        #pragma unroll
        for (int q = 0; q < 4; ++q) {
            va[q] = *(const short8*)(pxa[q] + k0);
            vb[q] = *(const short8*)(pwb[q] + k0);
        }

        __syncthreads();

        #pragma unroll
        for (int q = 0; q < 4; ++q) {
            *(short8*)&Ah[srow[q]][sko[q]] = va[q];
            *(short8*)&Bh[srow[q]][sko[q]] = vb[q];
        }

        __syncthreads();

        #pragma unroll
        for (int ks = 0; ks < 4; ++ks) {
            short8 ah[2], bh[2];
            #pragma unroll
            for (int t = 0; t < 2; ++t) {
                ah[t] = *(const short8*)&Ah[wr + t*32 + l31][ks*16 + lh*8];
                bh[t] = *(const short8*)&Bh[wc + t*32 + l31][ks*16 + lh*8];
            }
            #pragma unroll
            for (int mt = 0; mt < 2; ++mt)
                #pragma unroll
                for (int nt = 0; nt < 2; ++nt)
                    acc[mt][nt] = __builtin_amdgcn_mfma_f32_32x32x16_bf16(ah[mt], bh[nt], acc[mt][nt], 0, 0, 0);
        }
    }

    if (tid < GBM) rowcnt[tid] = 0;
    __syncthreads();

    // C/D: col = lane&31, row = (reg&3) + 8*(reg>>2) + 4*(lane>>5)
    #pragma unroll
    for (int mt = 0; mt < 2; ++mt)
        #pragma unroll
        for (int nt = 0; nt < 2; ++nt) {
            const int colg = bn + wc + nt*32 + l31;
            #pragma unroll
            for (int reg = 0; reg < 16; ++reg) {
                const int lr = wr + mt*32 + (reg & 3) + 8*(reg >> 2) + 4*lh;
                const int r  = bm + lr;
                const float vv = acc[mt][nt][reg];
                __builtin_nontemporal_store(vv, &z_pre[(size_t)r * NLAT + colg]);
                if (vv > THRESH) {
                    const int s = atomicAdd(&rowcnt[lr], 1);   // LDS atomic
                    if (s < SLOTS)
                        slot_iv[((size_t)r * NBLKN + blkn) * SLOTS + s] =
                            make_int2(colg, __float_as_int(vv));
                }
            }
        }

    // zero the z tile with nontemporal ext-vector stores
    const f32x4 zero4 = {0.f, 0.f, 0.f, 0.f};
    #pragma unroll
    for (int u = 0; u < 16; ++u) {
        const int idx = u * 256 + tid;
        const int lr = idx >> 5;
        const int lc = (idx & 31) * 4;
        f32x4* dst4 = (f32x4*)(z + (size_t)(bm + lr) * NLAT + bn + lc);
        __builtin_nontemporal_store(zero4, dst4);
    }

    __syncthreads();
    if (tid < GBM) cnt_blk[(size_t)blkn * BATCH + bm + tid] = rowcnt[tid];
}

// ---------------------------------------------------------------------------
// Merged select: classify + f64 refine + finalize + DECODER.
// r14: parallel prefix over block-columns + flat parallel slot gather
// (replaces the two serial sections of the r13-verified kernel).
// ---------------------------------------------------------------------------
__global__ __launch_bounds__(256) void select_kernel(const int* __restrict__ cnt_blk,
                                                     const int2* __restrict__ slot_iv,
                                                     const float* __restrict__ x,
                                                     const float* __restrict__ W_enc,
                                                     const float* __restrict__ bpre,
                                                     const unsigned short* __restrict__ wdh,
                                                     float* __restrict__ z,
                                                     float* __restrict__ x_hat,
                                                     float* __restrict__ recon,
                                                     int* __restrict__ idx_ws,
                                                     float* __restrict__ val_ws,
                                                     int* __restrict__ flag_ws)
{
    __shared__ int ccnt[NBLKN];
    __shared__ int cofs[NBLKN];
    __shared__ float cv[CAND_MAX];
    __shared__ int   ci[CAND_MAX];
    __shared__ unsigned char keep[CAND_MAX];
    __shared__ unsigned hist[256];
    __shared__ int b_sh, nsure_sh, namb_sh, of_sh, tot_sh, nk_sh;
    __shared__ int    amb_t[MAXAMB];
    __shared__ int    amb_i[MAXAMB];
    __shared__ double amb_d[MAXAMB];
    __shared__ int   t_idx[K_TOP + 8];
    __shared__ float t_val[K_TOP + 8];
    __shared__ int   kidx[K_TOP];
    __shared__ float kval[K_TOP];

    const int r = blockIdx.x;
    const int tid = threadIdx.x;

    if (tid == 0) { nsure_sh = 0; namb_sh = 0; nk_sh = 0; of_sh = 0; }
    hist[tid] = 0u;
    if (tid < NBLKN) ccnt[tid] = cnt_blk[(size_t)tid * BATCH + r];
    __syncthreads();

    // parallel exclusive prefix over 192 block-columns + overflow + total
    if (tid < NBLKN) {
        if (ccnt[tid] > SLOTS) atomicOr(&of_sh, 1);
        int s = 0;
        for (int b = 0; b < tid; ++b) s += ccnt[b];
        cofs[tid] = s;
        if (tid == NBLKN - 1) tot_sh = s + ccnt[tid];
    }
    __syncthreads();

    const int cnt = tot_sh;
    if (of_sh || cnt < K_TOP || cnt > CAND_MAX) {
        if (tid == 0) flag_ws[r] = 1;
        return;
    }

    // flat parallel slot gather: 2304 (blkn, slot) pairs over 256 threads
    for (int pq = tid; pq < NBLKN * SLOTS; pq += 256) {
        const int b = pq / SLOTS;
        const int e = pq - b * SLOTS;
        if (e < ccnt[b]) {
            const int2 iv = slot_iv[((size_t)r * NBLKN + b) * SLOTS + e];
            const int o = cofs[b] + e;
            ci[o] = iv.x;
            cv[o] = __int_as_float(iv.y);
        }
    }
    __syncthreads();

    for (int q = tid; q < cnt; q += 256) {
        int b = (int)(__float_as_uint(cv[q]) >> 16) - 16288;
        b = b < 0 ? 0 : (b > 255 ? 255 : b);
        atomicAdd(&hist[b], 1u);
    }
    __syncthreads();
    if (tid == 0) {
        int acc = 0, b = 255;
        for (; b >= 0; --b) {
            const int nb = acc + (int)hist[b];
            if (nb >= K_TOP) break;
            acc = nb;
        }
        b_sh = b;
    }
    __syncthreads();

    const int bstar = b_sh;
    const float hi = binedge(bstar + 1) + DELTA;
    const float lo = binedge(bstar) - DELTA;
    if (bstar >= 255 || bstar < 0 || lo <= THRESH + 1e-3f) {
        if (tid == 0) flag_ws[r] = 1;
        return;
    }

    for (int t = tid; t < cnt; t += 256) {
        const float vt = cv[t];
        unsigned char k = 0;
        if (vt > hi) { k = 1; atomicAdd(&nsure_sh, 1); }
        else if (vt >= lo) {
            const int p = atomicAdd(&namb_sh, 1);
            if (p < MAXAMB) { amb_t[p] = t; amb_i[p] = ci[t]; }
        }
        keep[t] = k;
    }
    __syncthreads();

    const int nsure = nsure_sh;
    const int namb = namb_sh;
    if (namb > MAXAMB || nsure >= K_TOP) { if (tid == 0) flag_ws[r] = 1; return; }
    const int nkeep_amb = K_TOP - nsure;

    // f64 refine (one wave per candidate, 4 waves rotating)
    const int lane = tid & 63, w = tid >> 6;
    const float* xrow = x + (size_t)r * D_IN;
    for (int q = w; q < namb; q += 4) {
        const float* wrow = W_enc + (size_t)amb_i[q] * D_IN;
        double a = 0.0;
        #pragma unroll
        for (int k = lane; k < D_IN; k += 64)
            a = fma((double)xrow[k] - (double)bpre[k], (double)wrow[k], a);
        #pragma unroll
        for (int off = 32; off; off >>= 1) a += __shfl_down(a, off, 64);
        if (lane == 0) amb_d[q] = a;
    }
    __syncthreads();

    for (int t = tid; t < namb; t += 256) {
        const double dv = amb_d[t];
        const int it = amb_i[t];
        int rk = 0;
        for (int q = 0; q < namb; ++q)
            rk += (amb_d[q] > dv) || (amb_d[q] == dv && amb_i[q] < it);
        if (rk < nkeep_amb) keep[amb_t[t]] = 1;
    }
    __syncthreads();

    for (int t = tid; t < cnt; t += 256) {
        if (keep[t]) {
            const int p = atomicAdd(&nk_sh, 1);
            if (p < K_TOP + 8) { t_idx[p] = ci[t]; t_val[p] = cv[t]; }
        }
    }
    __syncthreads();
    if (nk_sh != K_TOP) { if (tid == 0) flag_ws[r] = 1; return; }

    if (tid == 0) flag_ws[r] = 0;
    if (tid < K_TOP) {
        const int it = t_idx[tid];
        int pos = 0;
        #pragma unroll 8
        for (int s = 0; s < K_TOP; ++s) pos += (t_idx[s] < it);
        kidx[pos] = it;
        kval[pos] = t_val[tid];
        z[(size_t)r * NLAT + it] = t_val[tid];   // scatter over zeroed row
    }
    __syncthreads();

    // ---- fused decoder (deterministic: index-ascending sum) ----
    if (tid < D_IN / 4) {
        const int d0 = tid * 4;
        const float4 bp = *(const float4*)(bpre + d0);
        float a0 = bp.x, a1 = bp.y, a2 = bp.z, a3 = bp.w;
        #pragma unroll 8
        for (int j = 0; j < K_TOP; ++j) {
            const float vv = kval[j];
            const ushort4 w4 = *(const ushort4*)(wdh + (size_t)kidx[j] * D_IN + d0);
            a0 = fmaf(vv, bf2f(w4.x), a0);
            a1 = fmaf(vv, bf2f(w4.y), a1);
            a2 = fmaf(vv, bf2f(w4.z), a2);
            a3 = fmaf(vv, bf2f(w4.w), a3);
        }
        const size_t o = (size_t)r * D_IN + d0;
        const float4 xv = *(const float4*)(x + o);
        *(float4*)(x_hat + o) = make_float4(a0, a1, a2, a3);
        *(float4*)(recon + o) = make_float4(xv.x - a0, xv.y - a1, xv.z - a2, xv.w - a3);
    }
}

// ---------------------------------------------------------------------------
// Fallback full-row top-k (r3-verified).  Only flagged rows (or all if null).
// ---------------------------------------------------------------------------
__global__ __launch_bounds__(1024) void topk_fallback(const float* __restrict__ z_pre,
                                                      float* __restrict__ z,
                                                      const float* __restrict__ x,
                                                      const float* __restrict__ W_enc,
                                                      const float* __restrict__ bpre,
                                                      int* __restrict__ idx_ws,
                                                      float* __restrict__ val_ws,
                                                      const int* __restrict__ flag_ws)
{
    if (flag_ws != nullptr && flag_ws[blockIdx.x] == 0) return;

    __shared__ unsigned hist_w[16][257];
    __shared__ unsigned hist[256];
    __shared__ unsigned sh_prefix;
    __shared__ int sh_rem;
    __shared__ int cntA;
    __shared__ int nsure_sh;
    __shared__ int idxA[MAXA];
    __shared__ double dvalA[MAXA];
    __shared__ unsigned char keepA[MAXA];
    __shared__ int wcnt[16][24];

    const int r = blockIdx.x;
    const int tid = threadIdx.x;
    const int lane = tid & 63;
    const int w = tid >> 6;
    const unsigned long long lt = (1ull << lane) - 1ull;

    const float* src = z_pre + (size_t)r * NLAT;
    float v[24];
    #pragma unroll
    for (int c = 0; c < 24; ++c) v[c] = src[c*1024 + tid];

    if (tid == 0) { sh_prefix = 0u; sh_rem = K_TOP; cntA = 0; nsure_sh = 0; }
    if (idx_ws != nullptr && tid < K_TOP) {
        idx_ws[r*K_TOP + tid] = 0; val_ws[r*K_TOP + tid] = 0.0f;
    }

    for (int lvl = 0; lvl < 4; ++lvl) {
        const int shift = 24 - 8*lvl;
        for (int i = tid; i < 16*257; i += 1024) ((unsigned*)hist_w)[i] = 0u;
        __syncthreads();
        const unsigned pfx = sh_prefix;
        #pragma unroll
        for (int c = 0; c < 24; ++c) {
            const unsigned key = f2key(v[c]);
            const bool match = (lvl == 0) || ((key >> (shift + 8)) == (pfx >> (shift + 8)));
            if (match) atomicAdd(&hist_w[w][(key >> shift) & 255u], 1u);
        }
        __syncthreads();
        if (tid < 256) {
            unsigned s = 0;
            #pragma unroll
            for (int q = 0; q < 16; ++q) s += hist_w[q][tid];
            hist[tid] = s;
        }
        __syncthreads();
        if (tid == 0) {
            int rem = sh_rem, acc = 0, b = 255;
            for (; b >= 0; --b) {
                const int nb = acc + (int)hist[b];
                if (nb >= rem) { sh_rem = rem - acc; break; }
                acc = nb;
            }
            sh_prefix = pfx | ((unsigned)b << shift);
        }
        __syncthreads();
    }

    const float vT = key2f(sh_prefix);
    const float thr_lo = vT - DELTA, thr_hi = vT + DELTA;

    int wsure = 0;
    #pragma unroll
    for (int c = 0; c < 24; ++c) {
        const float val = v[c];
        const unsigned long long m = __ballot(val > thr_hi);
        if (lane == 0) wsure += (int)__popcll(m);
        if (val <= thr_hi && val >= thr_lo) {
            const int p = atomicAdd(&cntA, 1);
            if (p < MAXA) idxA[p] = c*1024 + tid;
        }
    }
    if (lane == 0 && wsure) atomicAdd(&nsure_sh, (unsigned)wsure);
    __syncthreads();

    const int nA = cntA < MAXA ? cntA : MAXA;
    const int nkeepA = K_TOP - nsure_sh;

    for (int q = w; q < nA; q += 16) {
        const int j = idxA[q];
        const float* wrow = W_enc + (size_t)j * D_IN;
        const float* xrow = x + (size_t)r * D_IN;
        double a = 0.0;
        for (int k = lane; k < D_IN; k += 64)
            a = fma((double)xrow[k] - (double)bpre[k], (double)wrow[k], a);
        #pragma unroll
        for (int off = 32; off; off >>= 1) a += __shfl_down(a, off, 64);
        if (lane == 0) dvalA[q] = a;
    }
    __syncthreads();

    for (int t = tid; t < nA; t += 1024) {
        const double dv = dvalA[t];
        const int ix = idxA[t];
        int rank = 0;
        for (int q = 0; q < nA; ++q)
            rank += (dvalA[q] > dv) || (dvalA[q] == dv && idxA[q] < ix);
        keepA[t] = (rank < nkeepA) ? 1 : 0;
    }
    __syncthreads();

    bool kp[24];
    #pragma unroll
    for (int c = 0; c < 24; ++c) {
        const float val = v[c];
        bool k = (val > thr_hi);
        if (!k && val >= thr_lo) {
            const int i = c*1024 + tid;
            for (int q = 0; q < nA; ++q)
                if (idxA[q] == i) { k = (keepA[q] != 0); break; }
        }
        kp[c] = k;
        const unsigned long long m = __ballot(k);
        if (lane == 0) wcnt[w][c] = (int)__popcll(m);
    }
    __syncthreads();
    if (tid == 0) {
        int run = 0;
        for (int c = 0; c < 24; ++c)
            #pragma unroll
            for (int q = 0; q < 16; ++q) { const int t = wcnt[q][c]; wcnt[q][c] = run; run += t; }
    }
    __syncthreads();

    float* zdst = z + (size_t)r * NLAT;
    #pragma unroll
    for (int c = 0; c < 24; ++c) {
        const unsigned long long m = __ballot(kp[c]);
        const int pos = wcnt[w][c] + (int)__popcll(m & lt);
        const int i = c*1024 + tid;
        zdst[i] = kp[c] ? v[c] : 0.0f;
        if (kp[c] && idx_ws != nullptr && pos < K_TOP) {
            idx_ws[r*K_TOP + pos] = i;
            val_ws[r*K_TOP + pos] = v[c];
        }
    }
}

// ---------------------------------------------------------------------------
// Flag-gated decoder for fallback rows.
// ---------------------------------------------------------------------------
__global__ __launch_bounds__(256) void dec_flagged(const int* __restrict__ flag_ws,
                                                   const int* __restrict__ idx_ws,
                                                   const float* __restrict__ val_ws,
                                                   const unsigned short* __restrict__ wdh,
                                                   const float* __restrict__ bpre,
                                                   const float* __restrict__ x,
                                                   float* __restrict__ x_hat,
                                                   float* __restrict__ recon)
{
    const int r = blockIdx.x;
    if (flag_ws[r] == 0) return;
    __shared__ int sidx[K_TOP];
    __shared__ float sval[K_TOP];
    const int tid = threadIdx.x;
    if (tid < K_TOP) {
        sidx[tid] = idx_ws[r*K_TOP + tid];
        sval[tid] = val_ws[r*K_TOP + tid];
    }
    __syncthreads();

    if (tid < D_IN / 4) {
        const int d0 = tid * 4;
        const float4 bp = *(const float4*)(bpre + d0);
        float a0 = bp.x, a1 = bp.y, a2 = bp.z, a3 = bp.w;
        #pragma unroll 8
        for (int j = 0; j < K_TOP; ++j) {
            const float vv = sval[j];
            const ushort4 w4 = *(const ushort4*)(wdh + (size_t)sidx[j] * D_IN + d0);
            a0 = fmaf(vv, bf2f(w4.x), a0);
            a1 = fmaf(vv, bf2f(w4.y), a1);
            a2 = fmaf(vv, bf2f(w4.z), a2);
            a3 = fmaf(vv, bf2f(w4.w), a3);
        }
        const size_t o = (size_t)r * D_IN + d0;
        const float4 xv = *(const float4*)(x + o);
        *(float4*)(x_hat + o) = make_float4(a0, a1, a2, a3);
        *(float4*)(recon + o) = make_float4(xv.x - a0, xv.y - a1, xv.z - a2, xv.w - a3);
    }
}

// ---------------------------------------------------------------------------
// Fallback GEMM with in-kernel split-2 (r5-verified) for small ws.
// ---------------------------------------------------------------------------
#define FBK 32
#define FLROW (FBK + 8)

__global__ __launch_bounds__(256) void enc_gemm_mfma(const float* __restrict__ x,
                                                     const float* __restrict__ W,
                                                     const float* __restrict__ bpre,
                                                     float* __restrict__ z_pre)
{
    __shared__ unsigned short Ah[GBM][FLROW], Al[GBM][FLROW];
    __shared__ unsigned short Bh[GBN][FLROW], Bl[GBN][FLROW];

    const int tid = threadIdx.x;
    const int bm = blockIdx.y * GBM;
    const int bn = blockIdx.x * GBN;
    const int lane = tid & 63;
    const int wv = tid >> 6;
    const int wr = (wv >> 1) * 64;
    const int wc = (wv & 1) * 64;
    const int fr = lane & 15;
    const int fg = lane >> 4;

    const int srow = tid >> 3;
    const int sk   = (tid & 7) * 4;

    f32x4 acc[4][4];
    #pragma unroll
    for (int i = 0; i < 4; ++i)
        #pragma unroll
        for (int j = 0; j < 4; ++j)
            #pragma unroll
            for (int e = 0; e < 4; ++e) acc[i][j][e] = 0.0f;

    for (int k0 = 0; k0 < D_IN; k0 += FBK) {
        float4 xa[4], wb[4];
        const float4 bp = *(const float4*)(bpre + k0 + sk);
        #pragma unroll
        for (int p = 0; p < 4; ++p) {
            xa[p] = *(const float4*)(x + (size_t)(bm + srow + 32*p) * D_IN + k0 + sk);
            wb[p] = *(const float4*)(W + (size_t)(bn + srow + 32*p) * D_IN + k0 + sk);
        }
        __syncthreads();
        #pragma unroll
        for (int p = 0; p < 4; ++p) {
            const float a0 = xa[p].x - bp.x, a1 = xa[p].y - bp.y,
                        a2 = xa[p].z - bp.z, a3 = xa[p].w - bp.w;
            const unsigned short h0 = bf16hi(a0), h1 = bf16hi(a1),
                                 h2 = bf16hi(a2), h3 = bf16hi(a3);
            *(ushort4*)&Ah[srow + 32*p][sk] = make_ushort4(h0, h1, h2, h3);
            *(ushort4*)&Al[srow + 32*p][sk] = make_ushort4(
                bf16hi(a0 - bf2f(h0)), bf16hi(a1 - bf2f(h1)),
                bf16hi(a2 - bf2f(h2)), bf16hi(a3 - bf2f(h3)));
            const float b0 = wb[p].x, b1 = wb[p].y, b2 = wb[p].z, b3 = wb[p].w;
            const unsigned short g0 = bf16hi(b0), g1 = bf16hi(b1),
                                 g2 = bf16hi(b2), g3 = bf16hi(b3);
            *(ushort4*)&Bh[srow + 32*p][sk] = make_ushort4(g0, g1, g2, g3);
            *(ushort4*)&Bl[srow + 32*p][sk] = make_ushort4(
                bf16hi(b0 - bf2f(g0)), bf16hi(b1 - bf2f(g1)),
                bf16hi(b2 - bf2f(g2)), bf16hi(b3 - bf2f(g3)));
        }
        __syncthreads();

        short8 ah[4], al[4], bh[4], bl[4];
        #pragma unroll
        for (int t = 0; t < 4; ++t) {
            ah[t] = *(const short8*)&Ah[wr + t*16 + fr][fg * 8];
            al[t] = *(const short8*)&Al[wr + t*16 + fr][fg * 8];
            bh[t] = *(const short8*)&Bh[wc + t*16 + fr][fg * 8];
            bl[t] = *(const short8*)&Bl[wc + t*16 + fr][fg * 8];
        }
        #pragma unroll
        for (int mt = 0; mt < 4; ++mt)
            #pragma unroll
            for (int nt = 0; nt < 4; ++nt) {
                acc[mt][nt] = __builtin_amdgcn_mfma_f32_16x16x32_bf16(ah[mt], bh[nt], acc[mt][nt], 0, 0, 0);
                acc[mt][nt] = __builtin_amdgcn_mfma_f32_16x16x32_bf16(ah[mt], bl[nt], acc[mt][nt], 0, 0, 0);
                acc[mt][nt] = __builtin_amdgcn_mfma_f32_16x16x32_bf16(al[mt], bh[nt], acc[mt][nt], 0, 0, 0);
            }
    }

    #pragma unroll
    for (int mt = 0; mt < 4; ++mt)
        #pragma unroll
        for (int j = 0; j < 4; ++j) {
            const int r = bm + wr + mt*16 + fg*4 + j;
            float* dst = z_pre + (size_t)r * NLAT + bn + wc;
            #pragma unroll
            for (int nt = 0; nt < 4; ++nt)
                dst[nt*16 + fr] = acc[mt][nt][j];
        }
}

__global__ __launch_bounds__(256) void dec_scan_kernel(const float* __restrict__ z,
                                                       const float* __restrict__ W_dec,
                                                       const float* __restrict__ bpre,
                                                       const float* __restrict__ x,
                                                       float* __restrict__ x_hat,
                                                       float* __restrict__ recon)
{
    __shared__ int sidx[K_TOP];
    __shared__ float sval[K_TOP];
    __shared__ int wcnt[4];
    __shared__ int base;
    const int r = blockIdx.x;
    const int tid = threadIdx.x;
    const int lane = tid & 63, w = tid >> 6;
    if (tid == 0) base = 0;
    __syncthreads();
    const float* zrow = z + (size_t)r * NLAT;
    for (int c = 0; c < NLAT; c += 256) {
        const float vv = zrow[c + tid];
        const bool nz = (vv != 0.0f);
        const unsigned long long m = __ballot(nz);
        if (lane == 0) wcnt[w] = __popcll(m);
        __syncthreads();
        int b = base;
        for (int j = 0; j < w; ++j) b += wcnt[j];
        const int pos = b + __popcll(m & ((1ull << lane) - 1ull));
        if (nz && pos < K_TOP) { sidx[pos] = c + tid; sval[pos] = vv; }
        __syncthreads();
        if (tid == 0) { int s = 0; for (int j = 0; j < 4; ++j) s += wcnt[j]; base += s; }
        __syncthreads();
    }
    const int n = base > K_TOP ? K_TOP : base;

    float a0 = bpre[tid], a1 = bpre[tid + 256], a2 = bpre[tid + 512];
    for (int j = 0; j < n; ++j) {
        const float vv = sval[j];
        const float* wr_ = W_dec + (size_t)sidx[j] * D_IN;
        a0 = fmaf(vv, wr_[tid],       a0);
        a1 = fmaf(vv, wr_[tid + 256], a1);
        a2 = fmaf(vv, wr_[tid + 512], a2);
    }
    const size_t o = (size_t)r * D_IN + tid;
    x_hat[o]       = a0;
    x_hat[o + 256] = a1;
    x_hat[o + 512] = a2;
    recon[o]       = x[o]       - a0;
    recon[o + 256] = x[o + 256] - a1;
    recon[o + 512] = x[o + 512] - a2;
}

// ---------------------------------------------------------------------------
extern "C" void kernel_launch(void* const* d_in, const int* in_sizes, int n_in,
                              void* d_out, int out_size, void* d_ws, size_t ws_size,
                              hipStream_t stream)
{
    const float* x     = (const float*)d_in[0];
    const float* W_enc = (const float*)d_in[1];
    const float* W_dec = (const float*)d_in[2];
    const float* bpre  = (const float*)d_in[3];

    float* out   = (float*)d_out;
    float* x_hat = out;
    float* z     = x_hat + (size_t)BATCH * D_IN;
    float* z_pre = z     + (size_t)BATCH * NLAT;
    float* recon = z_pre + (size_t)BATCH * NLAT;

    // ws layout
    char* p = (char*)d_ws;
    int*    flag_ws   = (int*)p;           p += (size_t)BATCH * 4;
    int*    idx_ws    = (int*)p;           p += (size_t)BATCH * K_TOP * 4;
    float*  val_ws    = (float*)p;         p += (size_t)BATCH * K_TOP * 4;
    p = (char*)(((size_t)p + 15) & ~(size_t)15);
    int*    cnt_blk   = (int*)p;           p += (size_t)NBLKN * BATCH * 4;
    int2*   slot_iv   = (int2*)p;          p += (size_t)BATCH * NBLKN * SLOTS * 8;
    unsigned short* xh  = (unsigned short*)p;    p += (size_t)BATCH * D_IN * 2;
    unsigned short* wh  = (unsigned short*)p;    p += (size_t)NLAT * D_IN * 2;
    unsigned short* wdh = (unsigned short*)p;    p += (size_t)NLAT * D_IN * 2;
    const size_t ws_full = (size_t)(p - (char*)d_ws);
    const bool have_full = (d_ws != nullptr) && (ws_size >= ws_full);

    if (have_full) {
        conv_all<<<XCHUNKS + 2 * WCHUNKS, 256, 0, stream>>>(
            (const float4*)x, bpre, (const float4*)W_enc, (const float4*)W_dec,
            (ushort4*)xh, (ushort4*)wh, (ushort4*)wdh);

        enc_gemm_fused<<<NWG, 256, 0, stream>>>(xh, wh, z_pre, z, cnt_blk, slot_iv);

        select_kernel<<<BATCH, 256, 0, stream>>>(cnt_blk, slot_iv, x, W_enc, bpre, wdh,
                                                 z, x_hat, recon, idx_ws, val_ws, flag_ws);
        topk_fallback<<<BATCH, 1024, 0, stream>>>(z_pre, z, x, W_enc, bpre,
                                                  idx_ws, val_ws, flag_ws);
        dec_flagged<<<BATCH, 256, 0, stream>>>(flag_ws, idx_ws, val_ws, wdh, bpre,
                                               x, x_hat, recon);
    } else {
        dim3 g1(NLAT / GBN, BATCH / GBM);
        enc_gemm_mfma<<<g1, 256, 0, stream>>>(x, W_enc, bpre, z_pre);
        topk_fallback<<<BATCH, 1024, 0, stream>>>(z_pre, z, x, W_enc, bpre,
                                                  nullptr, nullptr, nullptr);
        dec_scan_kernel<<<BATCH, 256, 0, stream>>>(z, W_dec, bpre, x, x_hat, recon);
    }
}